// Round 18
// baseline (41.627 us; speedup 1.0000x reference)
//
#include <hip/hip_runtime.h>
#include <hip/hip_bf16.h>

// LCN: B=512, C=1, H=W=280, K=S=28, F=10, SPAN=100 (10x10), DEC_IN=1000, OUT=10
// ROUND 18: R16 structure (2 dispatches, fused conv + atomicAdd into y) with
// the conv grid rebalanced 320 -> 640 blocks (8 batches each). 640 = 2x256+128
// -> max 3 half-blocks/CU (1.5 eq) vs 320's 2 full (2.0 eq): shorter tail.
#define HW      280
#define IMG     78400        // 280*280
#define KK      28
#define F_N     10
#define SPAN    100
#define OUT_N   10

typedef short s16x8 __attribute__((ext_vector_type(8)));   // 8 bf16 (4 VGPRs)
typedef float f32x4 __attribute__((ext_vector_type(4)));   // MFMA C/D

static __device__ __forceinline__ unsigned bits2(__hip_bfloat162 h) {
  return *reinterpret_cast<unsigned*>(&h);
}

// Raw barrier: LDS visibility only (lgkmcnt), NO vmcnt drain -- global loads
// stay in flight across the barrier (bypasses __syncthreads' vmcnt(0) drain).
#define RAW_BARRIER() asm volatile("s_waitcnt lgkmcnt(0)\ns_barrier" ::: "memory")

// wprep: wbuf[s][r][f 16][k 32] bf16 (k 28..31 zero; f 10..15 unwritten).
// Thread = one (f,s,r) row: src = cw + idx*28 is PERFECTLY LINEAR.
// idx<5120 also initializes y[b][o] = db[o] (conv atomicAdds into it; stream
// order makes the init visible before conv).
__global__ __launch_bounds__(256) void wprep(const float* __restrict__ cw,
                                             uint4* __restrict__ wbuf4,
                                             const float* __restrict__ db,
                                             float* __restrict__ y) {
  const int idx = blockIdx.x * 256 + (int)threadIdx.x;  // 0..28159
  if (idx < 5120) y[idx] = db[idx % OUT_N];             // y init
  if (idx >= 28000) return;
  const int fs = idx / 28;          // f*100 + s
  const int r  = idx - fs * 28;
  const int f  = fs / 100;
  const int s  = fs - f * 100;

  const float* src = cw + (size_t)idx * 28;   // 112B, 16B-aligned
  float v[28];
#pragma unroll
  for (int j = 0; j < 7; ++j)
    *reinterpret_cast<float4*>(&v[j * 4]) =
        *reinterpret_cast<const float4*>(src + j * 4);

  unsigned p[16];
#pragma unroll
  for (int k2 = 0; k2 < 14; ++k2)
    p[k2] = bits2(__float22bfloat162_rn(make_float2(v[2 * k2], v[2 * k2 + 1])));
  p[14] = 0u; p[15] = 0u;

  uint4* dst = wbuf4 + ((size_t)(s * 28 + r) * 16 + f) * 4;  // 64B aligned
  dst[0] = make_uint4(p[0],  p[1],  p[2],  p[3]);
  dst[1] = make_uint4(p[4],  p[5],  p[6],  p[7]);
  dst[2] = make_uint4(p[8],  p[9],  p[10], p[11]);
  dst[3] = make_uint4(p[12], p[13], p[14], p[15]);
}

// Fused conv+bias+relu+decoder. grid 640 = bg(64: 8 b) x hs(10).
// Pipeline identical to R16's passing kernel (28 rows, raw lgkm barriers,
// B-frags oldest vmem, x prefetch depth 2, K=784 in accumulators).
// A-tile has 8 batch rows; MFMA lanes l15>=8 read duplicate rows (l15&7) and
// their D rows are discarded duplicates. Epilogue: h_lds[100][8] -> 80-thread
// decoder -> device-scope atomicAdd into y.
__global__ __launch_bounds__(256, 4) void lcn_conv(
    const float* __restrict__ x, const unsigned short* __restrict__ wbuf,
    const float* __restrict__ cb, const float* __restrict__ dw,
    float* __restrict__ y) {
  const int bid = blockIdx.x;        // 0..639
  const int hs  = bid % 10;
  const int bg  = bid / 10;          // 0..63

  const int tid  = (int)threadIdx.x;
  const int lane = tid & 63;
  const int wid  = tid >> 6;
  const int l15  = lane & 15;
  const int l7   = l15 & 7;          // A row (lanes 8-15 duplicate 0-7)
  const int kg   = lane >> 4;        // 0..3

  __shared__ short xl[2][8 * 320];   // 10.2 KB double-buffered A-tile
  __shared__ float h_lds[100 * 8];   // relu'd conv out [d_local=f*10+ws][b8]
  __shared__ float dw_lds[1000];     // dw slice [o][f*10+ws] for this hs

  // stage dw slice (visibility covered by the prologue barrier + final sync)
  for (int i = tid; i < 1000; i += 256) {
    const int o  = i / 100, dl = i - o * 100;
    const int f  = dl / 10, ws = dl - f * 10;
    dw_lds[i] = dw[o * 1000 + f * 100 + hs * 10 + ws];
  }

  // zero the k-pad slots (k 28..31 of each ws), same swizzle as data
  for (int i = tid; i < 2 * 80; i += 256) {
    const int buf = i / 80, j = i - buf * 80;
    const int b = j / 10, ws = j - b * 10;
    const int sidx = (b * 320 + ws * 32 + 28) ^ ((b & 7) << 3);
    *reinterpret_cast<short4*>(&xl[buf][sidx]) = make_short4(0, 0, 0, 0);
  }

  const int nun = (wid < 2) ? 3 : 2;             // ws units per wave (3,3,2,2)
  const int wsl[3] = {wid, wid + 4, wid + 8};    // ws 10/11 hit pad s-slots, never MFMA'd

  f32x4 acc[3];
#pragma unroll
  for (int u = 0; u < 3; ++u) acc[u] = (f32x4){0.f, 0.f, 0.f, 0.f};

  const float* xbase = x + (size_t)bg * 8 * IMG + (size_t)(hs * KK) * HW;

  float4 stgA[3], stgB[3];

#define ISSUE(STG, R)                                                       \
  _Pragma("unroll")                                                         \
  for (int j = 0; j < 3; ++j) {                                             \
    const int i = tid + 256 * j;                                            \
    if (i < 560) {                                                          \
      const int b = i / 70, q = i - b * 70;                                 \
      STG[j] = *reinterpret_cast<const float4*>(                            \
          xbase + (size_t)b * IMG + (size_t)(R) * HW + q * 4);              \
    }                                                                       \
  }

#define COMMIT(STG, BUF)                                                    \
  _Pragma("unroll")                                                         \
  for (int j = 0; j < 3; ++j) {                                             \
    const int i = tid + 256 * j;                                            \
    if (i < 560) {                                                          \
      const int b = i / 70, q = i - b * 70;                                 \
      const int ws = q / 7, c4 = q - ws * 7;                                \
      const int sidx = (b * 320 + ws * 32 + c4 * 4) ^ ((b & 7) << 3);       \
      uint2 pk;                                                             \
      pk.x = bits2(__float22bfloat162_rn(make_float2(STG[j].x, STG[j].y))); \
      pk.y = bits2(__float22bfloat162_rn(make_float2(STG[j].z, STG[j].w))); \
      *reinterpret_cast<uint2*>(&xl[BUF][sidx]) = pk;                       \
    }                                                                       \
  }

#define BLOAD(BFR, RR)                                                      \
  _Pragma("unroll")                                                         \
  for (int u = 0; u < 3; ++u)                                               \
    BFR[u] = *reinterpret_cast<const s16x8*>(                               \
        wbuf + (size_t)((hs * 10 + wsl[u]) * 28 + (RR)) * 512 + l15 * 32 + kg * 8);

#define MFMAS(BFR, BUF)                                                     \
  _Pragma("unroll")                                                         \
  for (int u = 0; u < 3; ++u) {                                             \
    if (u < nun) {                                                          \
      const int sidx = (l7 * 320 + wsl[u] * 32 + kg * 8) ^ (l7 << 3);       \
      const s16x8 afr = *reinterpret_cast<const s16x8*>(&xl[BUF][sidx]);    \
      acc[u] = __builtin_amdgcn_mfma_f32_16x16x32_bf16(afr, BFR[u], acc[u], 0, 0, 0); \
    }                                                                       \
  }

  // prologue: rows 0 (A) and 1 (B) in flight; commit A; lgkm barrier
  ISSUE(stgA, 0)
  ISSUE(stgB, 1)
  COMMIT(stgA, 0)            // waits A's loads only (B stays in flight)
  RAW_BARRIER();

#pragma unroll 1
  for (int r2 = 0; r2 < 14; ++r2) {
    const int re = 2 * r2;
    // ---- even phase: compute row re from xl[0] ----
    s16x8 bfrE[3];
    BLOAD(bfrE, re)
    if (re + 2 < 28) { ISSUE(stgA, re + 2) }     // newest vmem, stays in flight
    MFMAS(bfrE, 0)
    COMMIT(stgB, 1)                              // row re+1 -> buf 1
    RAW_BARRIER();
    // ---- odd phase: compute row re+1 from xl[1] ----
    const int ro = re + 1;
    s16x8 bfrO[3];
    BLOAD(bfrO, ro)
    if (ro + 2 < 28) { ISSUE(stgB, ro + 2) }
    MFMAS(bfrO, 1)
    if (r2 < 13) {
      COMMIT(stgA, 0)                            // row ro+1 -> buf 0
      RAW_BARRIER();
    }
  }

  // ---- fused epilogue ----
  // D layout: row(b-off) = kg*4+j, col(f) = l15; rows 8-15 are duplicates of
  // 0-7 (A rows duplicated) -> only kg<2 rows are written.
  if (l15 < F_N && kg < 2) {
#pragma unroll
    for (int u = 0; u < 3; ++u) {
      if (u < nun) {
        const int ws = wsl[u];
        const float bias = cb[l15 * 100 + hs * 10 + ws];
        float4 hv;
        hv.x = fmaxf(acc[u][0] + bias, 0.f);
        hv.y = fmaxf(acc[u][1] + bias, 0.f);
        hv.z = fmaxf(acc[u][2] + bias, 0.f);
        hv.w = fmaxf(acc[u][3] + bias, 0.f);
        *reinterpret_cast<float4*>(&h_lds[(l15 * 10 + ws) * 8 + kg * 4]) = hv;
      }
    }
  }
  __syncthreads();

  // decoder: thread (b8, o) dots 100 d's from LDS (broadcast reads), then
  // device-scope atomicAdd of this hs-partial into y[b][o] (init'd to db).
  if (tid < 8 * OUT_N) {
    const int b8 = tid & 7;
    const int o  = tid >> 3;
    float a = 0.f;
#pragma unroll 10
    for (int dl = 0; dl < 100; ++dl)
      a = fmaf(h_lds[dl * 8 + b8], dw_lds[o * 100 + dl], a);
    atomicAdd(&y[(bg * 8 + b8) * OUT_N + o], a);
  }
}

extern "C" void kernel_launch(void* const* d_in, const int* in_sizes, int n_in,
                              void* d_out, int out_size, void* d_ws, size_t ws_size,
                              hipStream_t stream) {
  const float* x  = (const float*)d_in[0];   // [512,1,280,280]
  const float* cw = (const float*)d_in[1];   // [1000,1,28,28]
  const float* cb = (const float*)d_in[2];   // [1000,1]
  const float* dw = (const float*)d_in[3];   // [10,1000]
  const float* db = (const float*)d_in[4];   // [10]
  float* y = (float*)d_out;                  // [512,10]

  uint4* wbuf = (uint4*)d_ws;                // [102][28][16][16]u32 = 2.92 MB

  wprep   <<<dim3(110), dim3(256), 0, stream>>>(cw, wbuf, db, y);
  lcn_conv<<<dim3(640), dim3(256), 0, stream>>>(x, (const unsigned short*)wbuf,
                                                cb, dw, y);
}

// Round 19
// 39.984 us; speedup vs baseline: 1.0411x; 1.0411x over previous
//
#include <hip/hip_runtime.h>
#include <hip/hip_bf16.h>

// LCN: B=512, C=1, H=W=280, K=S=28, F=10, SPAN=100 (10x10), DEC_IN=1000, OUT=10
// ROUND 19: REVERT to the measured-best R16 kernel (40.13 us).
// Two dispatches: wprep (w->bf16 MFMA layout + y:=db init) and the fused
// conv320 (28 rows in MFMA accumulators, bias+relu+decoder epilogue,
// device-scope atomicAdd combine into y).
// Measured decomposition: conv ~27us (x stream 160.6MB @ ~6 TB/s effective,
// vs 6.5 TB/s balanced ceiling per R11 dup-ablation), wprep ~1.5, gap ~1.5,
// fixed graph/launch overhead ~10. Alternatives all measured worse:
// R12 3-dispatch 43.5 | R14 fence-handoff broken | R15 in-loop w-cvt 52.4 |
// R18 640-block rebalance 41.6.
#define HW      280
#define IMG     78400        // 280*280
#define KK      28
#define F_N     10
#define SPAN    100
#define OUT_N   10

typedef short s16x8 __attribute__((ext_vector_type(8)));   // 8 bf16 (4 VGPRs)
typedef float f32x4 __attribute__((ext_vector_type(4)));   // MFMA C/D

static __device__ __forceinline__ unsigned bits2(__hip_bfloat162 h) {
  return *reinterpret_cast<unsigned*>(&h);
}

// Raw barrier: LDS visibility only (lgkmcnt), NO vmcnt drain -- global loads
// stay in flight across the barrier (bypasses __syncthreads' vmcnt(0) drain).
#define RAW_BARRIER() asm volatile("s_waitcnt lgkmcnt(0)\ns_barrier" ::: "memory")

// wprep: wbuf[s][r][f 16][k 32] bf16 (k 28..31 zero; f 10..15 unwritten).
// Thread = one (f,s,r) row: src = cw + idx*28 is PERFECTLY LINEAR.
// idx<5120 also initializes y[b][o] = db[o] (conv atomicAdds into it; stream
// order makes the init visible before conv).
__global__ __launch_bounds__(256) void wprep(const float* __restrict__ cw,
                                             uint4* __restrict__ wbuf4,
                                             const float* __restrict__ db,
                                             float* __restrict__ y) {
  const int idx = blockIdx.x * 256 + (int)threadIdx.x;  // 0..28159
  if (idx < 5120) y[idx] = db[idx % OUT_N];             // y init
  if (idx >= 28000) return;
  const int fs = idx / 28;          // f*100 + s
  const int r  = idx - fs * 28;
  const int f  = fs / 100;
  const int s  = fs - f * 100;

  const float* src = cw + (size_t)idx * 28;   // 112B, 16B-aligned
  float v[28];
#pragma unroll
  for (int j = 0; j < 7; ++j)
    *reinterpret_cast<float4*>(&v[j * 4]) =
        *reinterpret_cast<const float4*>(src + j * 4);

  unsigned p[16];
#pragma unroll
  for (int k2 = 0; k2 < 14; ++k2)
    p[k2] = bits2(__float22bfloat162_rn(make_float2(v[2 * k2], v[2 * k2 + 1])));
  p[14] = 0u; p[15] = 0u;

  uint4* dst = wbuf4 + ((size_t)(s * 28 + r) * 16 + f) * 4;  // 64B aligned
  dst[0] = make_uint4(p[0],  p[1],  p[2],  p[3]);
  dst[1] = make_uint4(p[4],  p[5],  p[6],  p[7]);
  dst[2] = make_uint4(p[8],  p[9],  p[10], p[11]);
  dst[3] = make_uint4(p[12], p[13], p[14], p[15]);
}

// Fused conv+bias+relu+decoder. grid 320 = bg(32: 16 b) x hs(10).
// 28 rows in accumulators; raw lgkm barriers; B-frags oldest vmem; x prefetch
// depth 2. Epilogue: D-frags -> h_lds[100 d][16 b]; 160 threads dot the
// decoder and atomicAdd per-hs partials into y (device-scope, cross-XCD safe).
__global__ __launch_bounds__(256, 4) void lcn_conv(
    const float* __restrict__ x, const unsigned short* __restrict__ wbuf,
    const float* __restrict__ cb, const float* __restrict__ dw,
    float* __restrict__ y) {
  const int bid = blockIdx.x;        // 0..319
  const int hs  = bid % 10;
  const int bg  = bid / 10;          // 0..31

  const int tid  = (int)threadIdx.x;
  const int lane = tid & 63;
  const int wid  = tid >> 6;
  const int l15  = lane & 15;
  const int kg   = lane >> 4;        // 0..3

  __shared__ short xl[2][16 * 320];  // 20.5 KB double-buffered A-tile
  __shared__ float h_lds[100 * 16];  // relu'd conv out [d_local=f*10+ws][b16]
  __shared__ float dw_lds[1000];     // dw slice [o][f*10+ws] for this hs

  // stage dw slice (visibility covered by the prologue barrier + final sync)
  for (int i = tid; i < 1000; i += 256) {
    const int o  = i / 100, dl = i - o * 100;
    const int f  = dl / 10, ws = dl - f * 10;
    dw_lds[i] = dw[o * 1000 + f * 100 + hs * 10 + ws];
  }

  // zero the k-pad slots (k 28..31 of each ws), same swizzle as data
  for (int i = tid; i < 2 * 160; i += 256) {
    const int buf = i / 160, j = i - buf * 160;
    const int b = j / 10, ws = j - b * 10;
    const int sidx = (b * 320 + ws * 32 + 28) ^ ((b & 7) << 3);
    *reinterpret_cast<short4*>(&xl[buf][sidx]) = make_short4(0, 0, 0, 0);
  }

  const int nun = (wid < 2) ? 3 : 2;             // ws units per wave (3,3,2,2)
  const int wsl[3] = {wid, wid + 4, wid + 8};    // ws 10/11 hit pad s-slots, never MFMA'd

  f32x4 acc[3];
#pragma unroll
  for (int u = 0; u < 3; ++u) acc[u] = (f32x4){0.f, 0.f, 0.f, 0.f};

  const float* xbase = x + (size_t)bg * 16 * IMG + (size_t)(hs * KK) * HW;

  float4 stgA[5], stgB[5];

#define ISSUE(STG, R)                                                       \
  _Pragma("unroll")                                                         \
  for (int j = 0; j < 5; ++j) {                                             \
    const int i = tid + 256 * j;                                            \
    if (i < 1120) {                                                         \
      const int b = i / 70, q = i - b * 70;                                 \
      STG[j] = *reinterpret_cast<const float4*>(                            \
          xbase + (size_t)b * IMG + (size_t)(R) * HW + q * 4);              \
    }                                                                       \
  }

#define COMMIT(STG, BUF)                                                    \
  _Pragma("unroll")                                                         \
  for (int j = 0; j < 5; ++j) {                                             \
    const int i = tid + 256 * j;                                            \
    if (i < 1120) {                                                         \
      const int b = i / 70, q = i - b * 70;                                 \
      const int ws = q / 7, c4 = q - ws * 7;                                \
      const int sidx = (b * 320 + ws * 32 + c4 * 4) ^ ((b & 7) << 3);       \
      uint2 pk;                                                             \
      pk.x = bits2(__float22bfloat162_rn(make_float2(STG[j].x, STG[j].y))); \
      pk.y = bits2(__float22bfloat162_rn(make_float2(STG[j].z, STG[j].w))); \
      *reinterpret_cast<uint2*>(&xl[BUF][sidx]) = pk;                       \
    }                                                                       \
  }

#define BLOAD(BFR, RR)                                                      \
  _Pragma("unroll")                                                         \
  for (int u = 0; u < 3; ++u)                                               \
    BFR[u] = *reinterpret_cast<const s16x8*>(                               \
        wbuf + (size_t)((hs * 10 + wsl[u]) * 28 + (RR)) * 512 + l15 * 32 + kg * 8);

#define MFMAS(BFR, BUF)                                                     \
  _Pragma("unroll")                                                         \
  for (int u = 0; u < 3; ++u) {                                             \
    if (u < nun) {                                                          \
      const int sidx = (l15 * 320 + wsl[u] * 32 + kg * 8) ^ ((l15 & 7) << 3); \
      const s16x8 afr = *reinterpret_cast<const s16x8*>(&xl[BUF][sidx]);    \
      acc[u] = __builtin_amdgcn_mfma_f32_16x16x32_bf16(afr, BFR[u], acc[u], 0, 0, 0); \
    }                                                                       \
  }

  // prologue: rows 0 (A) and 1 (B) in flight; commit A; lgkm barrier
  ISSUE(stgA, 0)
  ISSUE(stgB, 1)
  COMMIT(stgA, 0)            // waits A's loads only (B stays in flight)
  RAW_BARRIER();

#pragma unroll 1
  for (int r2 = 0; r2 < 14; ++r2) {
    const int re = 2 * r2;
    // ---- even phase: compute row re from xl[0] ----
    s16x8 bfrE[3];
    BLOAD(bfrE, re)
    if (re + 2 < 28) { ISSUE(stgA, re + 2) }     // newest vmem, stays in flight
    MFMAS(bfrE, 0)
    COMMIT(stgB, 1)                              // row re+1 -> buf 1
    RAW_BARRIER();
    // ---- odd phase: compute row re+1 from xl[1] ----
    const int ro = re + 1;
    s16x8 bfrO[3];
    BLOAD(bfrO, ro)
    if (ro + 2 < 28) { ISSUE(stgB, ro + 2) }
    MFMAS(bfrO, 1)
    if (r2 < 13) {
      COMMIT(stgA, 0)                            // row ro+1 -> buf 0
      RAW_BARRIER();
    }
  }

  // ---- fused epilogue ----
  // D layout: row(b-off) = kg*4+j, col(f) = l15.
  if (l15 < F_N) {
#pragma unroll
    for (int u = 0; u < 3; ++u) {
      if (u < nun) {
        const int ws = wsl[u];
        const float bias = cb[l15 * 100 + hs * 10 + ws];
        float4 hv;
        hv.x = fmaxf(acc[u][0] + bias, 0.f);
        hv.y = fmaxf(acc[u][1] + bias, 0.f);
        hv.z = fmaxf(acc[u][2] + bias, 0.f);
        hv.w = fmaxf(acc[u][3] + bias, 0.f);
        *reinterpret_cast<float4*>(&h_lds[(l15 * 10 + ws) * 16 + kg * 4]) = hv;
      }
    }
  }
  __syncthreads();

  // decoder: thread (b16, o) dots 100 d's from LDS (broadcast reads), then
  // device-scope atomicAdd of this hs-partial into y[b][o] (init'd to db).
  if (tid < 16 * OUT_N) {
    const int b16 = tid & 15;
    const int o   = tid >> 4;
    float a = 0.f;
#pragma unroll 10
    for (int dl = 0; dl < 100; ++dl)
      a = fmaf(h_lds[dl * 16 + b16], dw_lds[o * 100 + dl], a);
    atomicAdd(&y[(bg * 16 + b16) * OUT_N + o], a);
  }
}

extern "C" void kernel_launch(void* const* d_in, const int* in_sizes, int n_in,
                              void* d_out, int out_size, void* d_ws, size_t ws_size,
                              hipStream_t stream) {
  const float* x  = (const float*)d_in[0];   // [512,1,280,280]
  const float* cw = (const float*)d_in[1];   // [1000,1,28,28]
  const float* cb = (const float*)d_in[2];   // [1000,1]
  const float* dw = (const float*)d_in[3];   // [10,1000]
  const float* db = (const float*)d_in[4];   // [10]
  float* y = (float*)d_out;                  // [512,10]

  uint4* wbuf = (uint4*)d_ws;                // [102][28][16][16]u32 = 2.92 MB

  wprep   <<<dim3(110), dim3(256), 0, stream>>>(cw, wbuf, db, y);
  lcn_conv<<<dim3(320), dim3(256), 0, stream>>>(x, (const unsigned short*)wbuf,
                                                cb, dw, y);
}